// Round 10
// baseline (353.428 us; speedup 1.0000x reference)
//
#include <hip/hip_runtime.h>
#include <cmath>

// ---------------------------------------------------------------------------
// Agent-attention block, MI355X gfx950.  Round 14: recombine measured-best
// pieces — R7's attn1 (TILES1_=4, 42.4us measured) + R8's fixed bias_pb.
// GEMMs: BK=64 single-buffer 2-barrier discipline + G4 swizzle (round 11).
// qkv channel layout: per head nh, q = nh*96+[0,32), k = +[32,64), v = +[64,96).
// ---------------------------------------------------------------------------

typedef __bf16 bf16;
typedef bf16 bf16x8 __attribute__((ext_vector_type(8)));
typedef float f32x4 __attribute__((ext_vector_type(4)));

__device__ __forceinline__ f32x4 MFMA16(bf16x8 a, bf16x8 b, f32x4 c) {
  return __builtin_amdgcn_mfma_f32_16x16x32_bf16(a, b, c, 0, 0, 0);
}

// async global->LDS, 16B per lane; LDS dst = base + lane*16 (wave-uniform base)
__device__ __forceinline__ void gll16(const bf16* g, bf16* l) {
  __builtin_amdgcn_global_load_lds(
      (const __attribute__((address_space(1))) void*)g,
      (__attribute__((address_space(3))) void*)l, 16, 0, 0);
}

constexpr int B_ = 16, C_ = 256, N_ = 4096;
constexpr int NH_ = 8, KD_ = 32, AG_ = 64, O3_ = 768;
constexpr int TILES1_ = 4;                   // attn1 split-N tiles (measured best)
constexpr int PSTRIDE_ = 64 + 64 + 64 * 32;  // 2176 floats per (bh,tile) partial
constexpr float SCALE_ = 0.17677669529663687f;  // 32^-0.5

// ------------------------- prep_w: BN-fold + bf16 --------------------------
__global__ __launch_bounds__(256) void prep_w_kernel(
    const float* __restrict__ qkv_w, const float* __restrict__ qkv_bn,
    const float* __restrict__ proj_w, const float* __restrict__ proj_bn,
    bf16* __restrict__ wqb, float* __restrict__ shq,
    bf16* __restrict__ wpb, float* __restrict__ shp) {
  int o = blockIdx.x, t = threadIdx.x;
  if (o < O3_) {
    float g = qkv_bn[o], bb = qkv_bn[O3_ + o], m = qkv_bn[2 * O3_ + o],
          v = qkv_bn[3 * O3_ + o];
    float s = g * rsqrtf(v + 1e-5f);
    wqb[(size_t)o * C_ + t] = (bf16)(qkv_w[(size_t)o * C_ + t] * s);
    if (t == 0) shq[o] = bb - m * s;
  } else {
    int p = o - O3_;
    float g = proj_bn[p], bb = proj_bn[C_ + p], m = proj_bn[2 * C_ + p],
          v = proj_bn[3 * C_ + p];
    float s = g * rsqrtf(v + 1e-5f);
    wpb[(size_t)p * C_ + t] = (bf16)(proj_w[(size_t)p * C_ + t] * s);
    if (t == 0) shp[p] = bb - m * s;
  }
}

// ------------------------------ bias kernels -------------------------------
// pbT layout [nh][n][g].  Block = (nh, 64-n tile); lane = n_local so
// ah is broadcast, aw coalesced, an bilerp corners broadcast (g uniform per
// iteration).  LDS [64][72] (144B stride: 16B-aligned rows), coalesced
// 2x4KB write-out.
__global__ __launch_bounds__(256) void bias_pb_kernel(
    const float* __restrict__ an, const float* __restrict__ ah,
    const float* __restrict__ aw, bf16* __restrict__ pbT) {
  __shared__ __align__(16) bf16 T[64][72];
  int nh = blockIdx.x, n0 = blockIdx.y * 64;
  int t = threadIdx.x, lane = t & 63, wave = t >> 6;
  int h = n0 >> 6;  // uniform (n0 is 64-aligned)
  int w = lane;
  float fy = (h + 0.5f) * (7.0f / 64.0f) - 0.5f;
  float fx = (w + 0.5f) * (7.0f / 64.0f) - 0.5f;
  float fy0 = floorf(fy), fx0 = floorf(fx);
  float wy = fy - fy0, wx = fx - fx0;
  int y0 = (int)fy0, x0 = (int)fx0;
  int y0c = min(max(y0, 0), 6), y1c = min(max(y0 + 1, 0), 6);
  int x0c = min(max(x0, 0), 6), x1c = min(max(x0 + 1, 0), 6);
#pragma unroll
  for (int gi = 0; gi < 16; gi++) {
    int g = wave * 16 + gi;
    const float* A = an + (nh * AG_ + g) * 49;
    float a00 = A[y0c * 7 + x0c], a01 = A[y0c * 7 + x1c];
    float a10 = A[y1c * 7 + x0c], a11 = A[y1c * 7 + x1c];
    float v = (1.0f - wy) * ((1.0f - wx) * a00 + wx * a01) +
              wy * ((1.0f - wx) * a10 + wx * a11);
    v += ah[(nh * AG_ + g) * 64 + h] + aw[(nh * AG_ + g) * 64 + w];
    T[lane][g] = (bf16)v;
  }
  __syncthreads();
  bf16* dst = pbT + ((size_t)nh * N_ + n0) * AG_;
#pragma unroll
  for (int p = 0; p < 2; p++) {
    int u = p * 256 + t;
    int row = u >> 3, seg = u & 7;
    uint4 val = *(const uint4*)&T[row][seg * 8];
    *(uint4*)(dst + (size_t)row * AG_ + seg * 8) = val;
  }
}

__device__ __forceinline__ float bilerp7(const float* __restrict__ A, int h, int w) {
  float fy = (h + 0.5f) * (7.0f / 64.0f) - 0.5f;
  float fx = (w + 0.5f) * (7.0f / 64.0f) - 0.5f;
  float fy0 = floorf(fy), fx0 = floorf(fx);
  float wy = fy - fy0, wx = fx - fx0;
  int y0 = (int)fy0, x0 = (int)fx0;
  int y0c = min(max(y0, 0), 6), y1c = min(max(y0 + 1, 0), 6);
  int x0c = min(max(x0, 0), 6), x1c = min(max(x0 + 1, 0), 6);
  float a00 = A[y0c * 7 + x0c], a01 = A[y0c * 7 + x1c];
  float a10 = A[y1c * 7 + x0c], a11 = A[y1c * 7 + x1c];
  return (1.0f - wy) * ((1.0f - wx) * a00 + wx * a01) +
         wy * ((1.0f - wx) * a10 + wx * a11);
}

__global__ __launch_bounds__(256) void bias_ab_kernel(
    const float* __restrict__ na, const float* __restrict__ ha,
    const float* __restrict__ wa, bf16* __restrict__ ab) {
  int tid = blockIdx.x * 256 + threadIdx.x;  // nh,n,g  (g fastest)
  int g = tid & 63;
  int n = (tid >> 6) & (N_ - 1);
  int nh = tid >> 18;
  int h = n >> 6, w = n & 63;
  float v = bilerp7(na + (nh * AG_ + g) * 49, h, w);
  ab[tid] = (bf16)(v + ha[(nh * 64 + h) * AG_ + g] + wa[(nh * 64 + w) * AG_ + g]);
}

// --------------------- transpose_x: [c][n] f32 -> [n][c] bf16 --------------
__global__ __launch_bounds__(256) void transpose_x_kernel(
    const float* __restrict__ x, bf16* __restrict__ xT) {
  __shared__ __align__(16) unsigned LDSd[64 * 36];
  int b = blockIdx.x, n0 = blockIdx.y * 64, c0 = blockIdx.z * 64;
  int t = threadIdx.x, n = t & 63, cp = t >> 6;
  const float* xb = x + ((size_t)b * C_ + c0) * N_ + n0;
#pragma unroll
  for (int j = 0; j < 8; j++) {
    int cpr = cp * 8 + j;  // c-pair index 0..31
    int c = cpr * 2;
    float f0 = xb[(size_t)c * N_ + n];
    float f1 = xb[(size_t)(c + 1) * N_ + n];
    union { bf16 h[2]; unsigned u; } pk;
    pk.h[0] = (bf16)f0; pk.h[1] = (bf16)f1;
    LDSd[n * 36 + cpr] = pk.u;
  }
  __syncthreads();
  int n2 = t >> 2, seg = t & 3;
  const unsigned* row = &LDSd[n2 * 36 + seg * 8];
  uint4 d0 = *(const uint4*)row;
  uint4 d1 = *(const uint4*)(row + 4);
  bf16* dst = xT + ((size_t)b * N_ + n0 + n2) * C_ + c0 + seg * 16;
  *(uint4*)dst = d0;
  *(uint4*)(dst + 8) = d1;
}

// ------------------------------ K1: qkv GEMM -------------------------------
// BK=64, single-buffer, 2 barriers/K-step, G4 swizzle (verified round 11).
__global__ __launch_bounds__(256) void qkv_gemm_kernel(
    const bf16* __restrict__ xT, const bf16* __restrict__ wqb,
    const float* __restrict__ shq, bf16* __restrict__ qT,
    bf16* __restrict__ kT, bf16* __restrict__ vv) {
  int nt = blockIdx.x * 128, ot = blockIdx.y * 128, b = blockIdx.z;
  __shared__ __align__(16) bf16 As[128][64];
  __shared__ __align__(16) bf16 Bs[128][64];
  int t = threadIdx.x, wave = t >> 6, lane = t & 63, quad = lane >> 4, l16 = lane & 15;
  int wm = (wave >> 1) * 64, wn = (wave & 1) * 64;
  int lr = lane >> 3;                                // row within 8-row gll group
  int lsw = ((lane & 7) ^ (lr & 7)) * 8;             // swizzled global elem col
  f32x4 acc[4][4];
#pragma unroll
  for (int mi = 0; mi < 4; mi++)
#pragma unroll
    for (int ni = 0; ni < 4; ni++) acc[mi][ni] = (f32x4){0.f, 0.f, 0.f, 0.f};
  const bf16* xTb = xT + (size_t)b * N_ * C_;
  for (int k0 = 0; k0 < 256; k0 += 64) {
    __syncthreads();
#pragma unroll
    for (int i = 0; i < 4; i++) {
      int r0 = wave * 32 + i * 8;  // 8-aligned
      gll16(wqb + (size_t)(ot + r0 + lr) * C_ + k0 + lsw, &As[r0][0]);
      gll16(xTb + (size_t)(nt + r0 + lr) * C_ + k0 + lsw, &Bs[r0][0]);
    }
    __syncthreads();
#pragma unroll
    for (int ks2 = 0; ks2 < 2; ks2++) {
      bf16x8 af[4], bfv[4];
#pragma unroll
      for (int mi = 0; mi < 4; mi++)
        af[mi] = *(const bf16x8*)&As[wm + mi * 16 + l16]
                                   [((ks2 * 4 + quad) ^ (l16 & 7)) * 8];
#pragma unroll
      for (int ni = 0; ni < 4; ni++)
        bfv[ni] = *(const bf16x8*)&Bs[wn + ni * 16 + l16]
                                    [((ks2 * 4 + quad) ^ (l16 & 7)) * 8];
#pragma unroll
      for (int mi = 0; mi < 4; mi++)
#pragma unroll
        for (int ni = 0; ni < 4; ni++)
          acc[mi][ni] = MFMA16(af[mi], bfv[ni], acc[mi][ni]);
    }
  }
#pragma unroll
  for (int mi = 0; mi < 4; mi++) {
    int o0 = ot + wm + mi * 16 + quad * 4;
    float4 s4 = *(const float4*)(shq + o0);
    float sh[4] = {s4.x, s4.y, s4.z, s4.w};
    int base16 = ot + wm + mi * 16;  // wave-uniform, 16-aligned
    int nh = base16 / 96;
    int rem = base16 % 96;
    int type = rem >> 5;             // 0=q, 1=k, 2=v
    int kdb = (rem & 31) + quad * 4; // kd of r=0
    if (type < 2) {
      bf16* dst = (type == 0 ? qT : kT) + ((size_t)(b * NH_ + nh) * N_) * KD_;
#pragma unroll
      for (int ni = 0; ni < 4; ni++) {
        int n = nt + wn + ni * 16 + l16;
        union { ushort4 u; bf16 e[4]; } pk;
#pragma unroll
        for (int r = 0; r < 4; r++) pk.e[r] = (bf16)(acc[mi][ni][r] + sh[r]);
        *(ushort4*)(dst + (size_t)n * KD_ + kdb) = pk.u;
      }
    } else {
      bf16* dst = vv + ((size_t)(b * NH_ + nh) * KD_) * N_;
#pragma unroll
      for (int ni = 0; ni < 4; ni++) {
        int n = nt + wn + ni * 16 + l16;
#pragma unroll
        for (int r = 0; r < 4; r++)
          dst[(size_t)(kdb + r) * N_ + n] = (bf16)(acc[mi][ni][r] + sh[r]);
      }
    }
  }
}

// ------------------------------ K2: agent pooling --------------------------
__global__ __launch_bounds__(256) void pool_kernel(
    const bf16* __restrict__ qT, bf16* __restrict__ aT) {
  int tid = blockIdx.x * 256 + threadIdx.x;  // (((b*8+nh2)*64+g)*32+kd2)
  int kd2 = tid & 31;
  int g = (tid >> 5) & 63;
  int nh2 = (tid >> 11) & 7;
  int b = tid >> 14;
  int c = nh2 * KD_ + kd2;
  int ho = g >> 3, wo = g & 7;
  int ww = c & 63, ch = c >> 6;
  const bf16* qb = qT + ((size_t)(b * NH_ + ho) * N_) * KD_;
  float s = 0.f;
#pragma unroll
  for (int wi = 0; wi < 8; wi++) {
    int w_ = wo * 8 + wi;
    int n1 = ((w_ & 15) * 4 + ch) * 64 + ww;
    int kdlo = w_ >> 4;
#pragma unroll
    for (int hi = 0; hi < 8; hi++)
      s += (float)qb[(size_t)n1 * KD_ + kdlo + hi * 4];
  }
  aT[tid] = (bf16)(s * (1.0f / 64.0f));
}

// ------------------------------ K3: attn1 flash-style ----------------------
// Grid (TILES1_=4, 128).  Per block: 1024 n; per wave: 4 online iterations of
// 64 n with running (m, l) and rescaled oacc — all wave-private.
struct SM3comb { float m[4][64]; float l[4][64]; float o[4][64][33]; };
union SM3u { bf16 Ps[4][64][72]; SM3comb c; };

__global__ __launch_bounds__(256) void attn1_kernel(
    const bf16* __restrict__ kT, const bf16* __restrict__ vv,
    const bf16* __restrict__ aT, const bf16* __restrict__ pbT,
    float* __restrict__ part) {
  __shared__ __align__(16) SM3u sm;
  int tile = blockIdx.x, bh = blockIdx.y, nh = bh & 7;
  int t = threadIdx.x, wave = t >> 6, lane = t & 63, quad = lane >> 4, l16 = lane & 15;
  const bf16* aTb = aT + (size_t)bh * (AG_ * KD_);
  const bf16* kb = kT + (size_t)bh * N_ * KD_;
  const bf16* vb = vv + (size_t)bh * KD_ * N_;
  const bf16* pbh = pbT + (size_t)nh * N_ * AG_;  // [n][g]
  bf16x8 af[4];
#pragma unroll
  for (int mi = 0; mi < 4; mi++)
    af[mi] = *(const bf16x8*)(aTb + (mi * 16 + l16) * KD_ + quad * 8);
  float mrow[4][4], lrow[4][4];
  f32x4 zero4 = (f32x4){0.f, 0.f, 0.f, 0.f};
  f32x4 oacc[4][2];
#pragma unroll
  for (int mi = 0; mi < 4; mi++) {
    oacc[mi][0] = zero4; oacc[mi][1] = zero4;
#pragma unroll
    for (int r = 0; r < 4; r++) { mrow[mi][r] = -1e30f; lrow[mi][r] = 0.f; }
  }
  for (int it = 0; it < 4; it++) {
    int ng = tile * 1024 + wave * 256 + it * 64;
    bf16x8 kf[4];
#pragma unroll
    for (int ni = 0; ni < 4; ni++)
      kf[ni] = *(const bf16x8*)(kb + (size_t)(ng + ni * 16 + l16) * KD_ + quad * 8);
#pragma unroll
    for (int mi = 0; mi < 4; mi++) {
      f32x4 s[4];
#pragma unroll
      for (int ni = 0; ni < 4; ni++) s[ni] = MFMA16(af[mi], kf[ni], zero4);
      int g0 = mi * 16 + quad * 4;
#pragma unroll
      for (int ni = 0; ni < 4; ni++) {
        union { ushort4 u; bf16 e[4]; } pv4;
        pv4.u = *(const ushort4*)(pbh + (size_t)(ng + ni * 16 + l16) * AG_ + g0);
#pragma unroll
        for (int r = 0; r < 4; r++)
          s[ni][r] = s[ni][r] * SCALE_ + (float)pv4.e[r];
      }
      float fac[4];
#pragma unroll
      for (int r = 0; r < 4; r++) {
        float mx = fmaxf(fmaxf(s[0][r], s[1][r]), fmaxf(s[2][r], s[3][r]));
#pragma unroll
        for (int off = 1; off < 16; off <<= 1) mx = fmaxf(mx, __shfl_xor(mx, off));
        float newm = fmaxf(mrow[mi][r], mx);
        float rs = 0.f;
#pragma unroll
        for (int ni = 0; ni < 4; ni++) {
          float pv = __expf(s[ni][r] - newm);
          s[ni][r] = pv; rs += pv;
        }
#pragma unroll
        for (int off = 1; off < 16; off <<= 1) rs += __shfl_xor(rs, off);
        float f = __expf(mrow[mi][r] - newm);
        lrow[mi][r] = lrow[mi][r] * f + rs;
        mrow[mi][r] = newm;
        fac[r] = f;
      }
#pragma unroll
      for (int ci = 0; ci < 2; ci++)
#pragma unroll
        for (int r = 0; r < 4; r++) oacc[mi][ci][r] *= fac[r];
#pragma unroll
      for (int ni = 0; ni < 4; ni++)
#pragma unroll
        for (int r = 0; r < 4; r++)
          sm.Ps[wave][mi * 16 + quad * 4 + r][ni * 16 + l16] = (bf16)s[ni][r];
    }
#pragma unroll
    for (int ks = 0; ks < 2; ks++) {
      bf16x8 vf[2], pf[4];
#pragma unroll
      for (int ci = 0; ci < 2; ci++)
        vf[ci] = *(const bf16x8*)(vb + (size_t)(ci * 16 + l16) * N_ + ng + ks * 32 + quad * 8);
#pragma unroll
      for (int mi = 0; mi < 4; mi++)
        pf[mi] = *(const bf16x8*)&sm.Ps[wave][mi * 16 + l16][ks * 32 + quad * 8];
#pragma unroll
      for (int mi = 0; mi < 4; mi++)
#pragma unroll
        for (int ci = 0; ci < 2; ci++)
          oacc[mi][ci] = MFMA16(pf[mi], vf[ci], oacc[mi][ci]);
    }
  }
  __syncthreads();  // all waves done with Ps; union switches to comb
#pragma unroll
  for (int mi = 0; mi < 4; mi++)
#pragma unroll
    for (int r = 0; r < 4; r++) {
      int g = mi * 16 + quad * 4 + r;
      if (l16 == 0) { sm.c.m[wave][g] = mrow[mi][r]; sm.c.l[wave][g] = lrow[mi][r]; }
      sm.c.o[wave][g][l16] = oacc[mi][0][r];
      sm.c.o[wave][g][16 + l16] = oacc[mi][1][r];
    }
  __syncthreads();
  {
    int g = t >> 2, kd0 = (t & 3) * 8;
    float M = fmaxf(fmaxf(sm.c.m[0][g], sm.c.m[1][g]), fmaxf(sm.c.m[2][g], sm.c.m[3][g]));
    float ew[4], L = 0.f;
#pragma unroll
    for (int w2 = 0; w2 < 4; w2++) {
      ew[w2] = __expf(sm.c.m[w2][g] - M);
      L += sm.c.l[w2][g] * ew[w2];
    }
    float* pt = part + (size_t)(bh * TILES1_ + tile) * PSTRIDE_;
    if ((t & 3) == 0) { pt[g] = M; pt[64 + g] = L; }
    float4 o0, o1;
    o0.x = o0.y = o0.z = o0.w = 0.f; o1 = o0;
#pragma unroll
    for (int w2 = 0; w2 < 4; w2++) {
      float e = ew[w2];
      const float* src = &sm.c.o[w2][g][kd0];
      o0.x += src[0] * e; o0.y += src[1] * e; o0.z += src[2] * e; o0.w += src[3] * e;
      o1.x += src[4] * e; o1.y += src[5] * e; o1.z += src[6] * e; o1.w += src[7] * e;
    }
    *(float4*)(pt + 128 + g * 32 + kd0) = o0;
    *(float4*)(pt + 128 + g * 32 + kd0 + 4) = o1;
  }
}

// ------------------------------ K3b: combine partials ----------------------
__global__ __launch_bounds__(256) void attn1_combine_kernel(
    const float* __restrict__ part, bf16* __restrict__ attnT) {
  int bh = blockIdx.x, t = threadIdx.x;
  int g = t >> 2, kd0 = (t & 3) * 8;
  const float* base = part + (size_t)bh * TILES1_ * PSTRIDE_;
  float gm = -1e30f, L = 0.f;
  float o[8];
#pragma unroll
  for (int j = 0; j < 8; j++) o[j] = 0.f;
  for (int tl = 0; tl < TILES1_; tl++) {
    const float* pt = base + tl * PSTRIDE_;
    float m = pt[g], l = pt[64 + g];
    float nm = fmaxf(gm, m);
    float a0 = __expf(gm - nm), a1 = __expf(m - nm);
    L = L * a0 + l * a1;
    float4 x0 = *(const float4*)(pt + 128 + g * 32 + kd0);
    float4 x1 = *(const float4*)(pt + 128 + g * 32 + kd0 + 4);
    o[0] = o[0] * a0 + x0.x * a1; o[1] = o[1] * a0 + x0.y * a1;
    o[2] = o[2] * a0 + x0.z * a1; o[3] = o[3] * a0 + x0.w * a1;
    o[4] = o[4] * a0 + x1.x * a1; o[5] = o[5] * a0 + x1.y * a1;
    o[6] = o[6] * a0 + x1.z * a1; o[7] = o[7] * a0 + x1.w * a1;
    gm = nm;
  }
  float inv = 1.0f / L;
  bf16* dst = attnT + (size_t)bh * (KD_ * AG_);
#pragma unroll
  for (int j = 0; j < 8; j++)
    dst[(kd0 + j) * AG_ + g] = (bf16)(o[j] * inv);
}

// ------------------------------ K4: stage 2 --------------------------------
__global__ __launch_bounds__(256) void attn2_kernel(
    const bf16* __restrict__ qT, const bf16* __restrict__ aT,
    const bf16* __restrict__ attnT, const bf16* __restrict__ ab,
    bf16* __restrict__ outa) {
  __shared__ __align__(16) bf16 Ps[4][64][72];
  int nt = blockIdx.x * 256;
  int bh = blockIdx.y, b = bh >> 3, nh = bh & 7;
  int t = threadIdx.x, wave = t >> 6, lane = t & 63, quad = lane >> 4, l16 = lane & 15;
  const bf16* qb = qT + (size_t)bh * N_ * KD_;
  const bf16* aTb = aT + (size_t)bh * (AG_ * KD_);
  const bf16* atb = attnT + (size_t)bh * (KD_ * AG_);
  bf16x8 afr[4], tfr[2][2];
#pragma unroll
  for (int gi = 0; gi < 4; gi++)
    afr[gi] = *(const bf16x8*)(aTb + (gi * 16 + l16) * KD_ + quad * 8);
#pragma unroll
  for (int ci = 0; ci < 2; ci++)
#pragma unroll
    for (int ks = 0; ks < 2; ks++)
      tfr[ci][ks] = *(const bf16x8*)(atb + (ci * 16 + l16) * AG_ + ks * 32 + quad * 8);
  const bf16* abh = ab + (size_t)nh * N_ * AG_;
  int nloc = wave * 64;
  f32x4 zero4 = (f32x4){0.f, 0.f, 0.f, 0.f};
#pragma unroll
  for (int mi = 0; mi < 4; mi++) {
    bf16x8 qf = *(const bf16x8*)(qb + (size_t)(nt + nloc + mi * 16 + l16) * KD_ + quad * 8);
    f32x4 s[4];
#pragma unroll
    for (int gi = 0; gi < 4; gi++)
      s[gi] = MFMA16(qf, afr[gi], zero4);
    int n0 = nt + nloc + mi * 16 + quad * 4;
#pragma unroll
    for (int gi = 0; gi < 4; gi++) {
      int g = gi * 16 + l16;
#pragma unroll
      for (int r = 0; r < 4; r++)
        s[gi][r] = s[gi][r] * SCALE_ + (float)abh[(size_t)(n0 + r) * AG_ + g];
    }
#pragma unroll
    for (int r = 0; r < 4; r++) {
      float mx = fmaxf(fmaxf(s[0][r], s[1][r]), fmaxf(s[2][r], s[3][r]));
#pragma unroll
      for (int off = 1; off < 16; off <<= 1) mx = fmaxf(mx, __shfl_xor(mx, off));
      float rs = 0.f;
#pragma unroll
      for (int gi = 0; gi < 4; gi++) {
        float p = __expf(s[gi][r] - mx);
        s[gi][r] = p; rs += p;
      }
#pragma unroll
      for (int off = 1; off < 16; off <<= 1) rs += __shfl_xor(rs, off);
      float inv = 1.0f / rs;
#pragma unroll
      for (int gi = 0; gi < 4; gi++) s[gi][r] *= inv;
    }
#pragma unroll
    for (int gi = 0; gi < 4; gi++)
#pragma unroll
      for (int r = 0; r < 4; r++)
        Ps[wave][mi * 16 + quad * 4 + r][gi * 16 + l16] = (bf16)s[gi][r];
  }
  __syncthreads();
  f32x4 O[4][2];
#pragma unroll
  for (int mi = 0; mi < 4; mi++) { O[mi][0] = zero4; O[mi][1] = zero4; }
#pragma unroll
  for (int ks = 0; ks < 2; ks++) {
    bf16x8 pf[4];
#pragma unroll
    for (int mi = 0; mi < 4; mi++)
      pf[mi] = *(const bf16x8*)&Ps[wave][mi * 16 + l16][ks * 32 + quad * 8];
#pragma unroll
    for (int mi = 0; mi < 4; mi++)
#pragma unroll
      for (int ci = 0; ci < 2; ci++)
        O[mi][ci] = MFMA16(pf[mi], tfr[ci][ks], O[mi][ci]);
  }
  bf16* ob = outa + (size_t)b * C_ * N_;
#pragma unroll
  for (int mi = 0; mi < 4; mi++) {
    int n0 = nt + nloc + mi * 16 + quad * 4;
#pragma unroll
    for (int ci = 0; ci < 2; ci++) {
      int c = nh * KD_ + ci * 16 + l16;
      union { ushort4 u; bf16 e[4]; } pk;
#pragma unroll
      for (int r = 0; r < 4; r++) pk.e[r] = (bf16)O[mi][ci][r];
      *(ushort4*)(ob + (size_t)c * N_ + n0) = pk.u;
    }
  }
}

// -------------- K5: fused pe dwconv + add + transpose (LDS-staged) ---------
__global__ __launch_bounds__(256) void pe_tr_kernel(
    const bf16* __restrict__ vv, const bf16* __restrict__ outa,
    const float* __restrict__ pw, const float* __restrict__ bn,
    bf16* __restrict__ hT) {
  __shared__ __align__(16) bf16 Vs[3][64][68];
  __shared__ __align__(16) bf16 Os[64][68];
  int b = blockIdx.x, n0 = blockIdx.y * 64, c0 = blockIdx.z * 64;
  int h = n0 >> 6;
  int t = threadIdx.x;
#pragma unroll
  for (int dy = 0; dy < 3; dy++) {
    int hh = h + dy - 1;
    bool ok = (unsigned)hh < 64u;
#pragma unroll
    for (int it = 0; it < 2; it++) {
      int u = it * 256 + t;
      int c = u >> 3, seg = u & 7;  // 64 c x 8 segs of 16B
      union { uint4 q; uint2 d[2]; } val;
      val.q = make_uint4(0u, 0u, 0u, 0u);
      if (ok)
        val.q = *(const uint4*)(vv + ((size_t)b * C_ + c0 + c) * N_ + hh * 64 + seg * 8);
      *(uint2*)&Vs[dy][c][seg * 8] = val.d[0];
      *(uint2*)&Vs[dy][c][seg * 8 + 4] = val.d[1];
    }
  }
#pragma unroll
  for (int it = 0; it < 2; it++) {
    int u = it * 256 + t;
    int c = u >> 3, seg = u & 7;
    union { uint4 q; uint2 d[2]; } val;
    val.q = *(const uint4*)(outa + ((size_t)b * C_ + c0 + c) * N_ + n0 + seg * 8);
    *(uint2*)&Os[c][seg * 8] = val.d[0];
    *(uint2*)&Os[c][seg * 8 + 4] = val.d[1];
  }
  __syncthreads();
  int cl = t & 63, wv = t >> 6;
  int c = c0 + cl;
  const float* wc = pw + c * 9;
  float w00 = wc[0], w01 = wc[1], w02 = wc[2];
  float w10 = wc[3], w11 = wc[4], w12 = wc[5];
  float w20 = wc[6], w21 = wc[7], w22 = wc[8];
  float sc = bn[c] * rsqrtf(bn[3 * C_ + c] + 1e-5f);
  float sh = bn[C_ + c] - bn[2 * C_ + c] * sc;
#pragma unroll
  for (int half = 0; half < 2; half++) {
    int oct = half * 4 + wv;   // 0..7, wave-uniform
    int w0 = oct * 8;
    float r[3][10];
#pragma unroll
    for (int dy = 0; dy < 3; dy++) {
      union { uint2 q; bf16 e[4]; } lo, hi;
      lo.q = *(const uint2*)&Vs[dy][cl][w0];
      hi.q = *(const uint2*)&Vs[dy][cl][w0 + 4];
#pragma unroll
      for (int j = 0; j < 4; j++) {
        r[dy][j + 1] = (float)lo.e[j];
        r[dy][j + 5] = (float)hi.e[j];
      }
      r[dy][0] = (w0 > 0) ? (float)Vs[dy][cl][w0 - 1] : 0.f;
      r[dy][9] = (w0 < 56) ? (float)Vs[dy][cl][w0 + 8] : 0.f;
    }
    union { uint2 q; bf16 e[4]; } plo, phi;
    plo.q = *(const uint2*)&Os[cl][w0];
    phi.q = *(const uint2*)&Os[cl][w0 + 4];
    bf16* dst = hT + ((size_t)b * N_ + n0 + w0) * C_ + c;
#pragma unroll
    for (int j = 0; j < 8; j++) {
      float a = r[0][j] * w00 + r[0][j + 1] * w01 + r[0][j + 2] * w02 +
                r[1][j] * w10 + r[1][j + 1] * w11 + r[1][j + 2] * w12 +
                r[2][j] * w20 + r[2][j + 1] * w21 + r[2][j + 2] * w22;
      float po = (j < 4) ? (float)plo.e[j] : (float)phi.e[j - 4];
      dst[(size_t)j * C_] = (bf16)(po + a * sc + sh);
    }
  }
}

// ------------------------------ K6: proj GEMM -------------------------------
__global__ __launch_bounds__(256) void proj_gemm_kernel(
    const bf16* __restrict__ hT, const bf16* __restrict__ wpb,
    const float* __restrict__ shp, float* __restrict__ out) {
  int nt = blockIdx.x * 128, ot = blockIdx.y * 128, b = blockIdx.z;
  __shared__ __align__(16) bf16 As[128][64];
  __shared__ __align__(16) bf16 Bs[128][64];
  int t = threadIdx.x, wave = t >> 6, lane = t & 63, quad = lane >> 4, l16 = lane & 15;
  int wm = (wave >> 1) * 64, wn = (wave & 1) * 64;
  int lr = lane >> 3;
  int lsw = ((lane & 7) ^ (lr & 7)) * 8;
  f32x4 acc[4][4];
#pragma unroll
  for (int mi = 0; mi < 4; mi++)
#pragma unroll
    for (int ni = 0; ni < 4; ni++) acc[mi][ni] = (f32x4){0.f, 0.f, 0.f, 0.f};
  const bf16* hTb = hT + (size_t)b * N_ * C_;
  for (int k0 = 0; k0 < 256; k0 += 64) {
    __syncthreads();
#pragma unroll
    for (int i = 0; i < 4; i++) {
      int r0 = wave * 32 + i * 8;
      gll16(wpb + (size_t)(ot + r0 + lr) * C_ + k0 + lsw, &As[r0][0]);
      gll16(hTb + (size_t)(nt + r0 + lr) * C_ + k0 + lsw, &Bs[r0][0]);
    }
    __syncthreads();
#pragma unroll
    for (int ks2 = 0; ks2 < 2; ks2++) {
      bf16x8 af[4], bfv[4];
#pragma unroll
      for (int mi = 0; mi < 4; mi++)
        af[mi] = *(const bf16x8*)&As[wm + mi * 16 + l16]
                                   [((ks2 * 4 + quad) ^ (l16 & 7)) * 8];
#pragma unroll
      for (int ni = 0; ni < 4; ni++)
        bfv[ni] = *(const bf16x8*)&Bs[wn + ni * 16 + l16]
                                    [((ks2 * 4 + quad) ^ (l16 & 7)) * 8];
#pragma unroll
      for (int mi = 0; mi < 4; mi++)
#pragma unroll
        for (int ni = 0; ni < 4; ni++)
          acc[mi][ni] = MFMA16(af[mi], bfv[ni], acc[mi][ni]);
    }
  }
  float* ob = out + (size_t)b * C_ * N_;
#pragma unroll
  for (int mi = 0; mi < 4; mi++) {
    int o0 = ot + wm + mi * 16 + quad * 4;
    float4 s4 = *(const float4*)(shp + o0);
    float sh[4] = {s4.x, s4.y, s4.z, s4.w};
#pragma unroll
    for (int ni = 0; ni < 4; ni++) {
      int n = nt + wn + ni * 16 + l16;
#pragma unroll
      for (int r = 0; r < 4; r++)
        ob[(size_t)(o0 + r) * N_ + n] = acc[mi][ni][r] + sh[r];
    }
  }
}

// ------------------------------ launcher -----------------------------------
extern "C" void kernel_launch(void* const* d_in, const int* in_sizes, int n_in,
                              void* d_out, int out_size, void* d_ws, size_t ws_size,
                              hipStream_t stream) {
  const float* x = (const float*)d_in[0];
  const float* qkv_w = (const float*)d_in[1];
  const float* qkv_bn = (const float*)d_in[2];
  const float* pe_w = (const float*)d_in[3];
  const float* pe_bn = (const float*)d_in[4];
  const float* proj_w = (const float*)d_in[5];
  const float* proj_bn = (const float*)d_in[6];
  const float* an_bias = (const float*)d_in[7];
  const float* na_bias = (const float*)d_in[8];
  const float* ah_bias = (const float*)d_in[9];
  const float* aw_bias = (const float*)d_in[10];
  const float* ha_bias = (const float*)d_in[11];
  const float* wa_bias = (const float*)d_in[12];

  char* ws = (char*)d_ws;
  bf16* qT = (bf16*)(ws + 0);                 //  33,554,432
  bf16* kT = (bf16*)(ws + 33554432);          //  33,554,432 (later houT)
  bf16* vv = (bf16*)(ws + 67108864);          //  33,554,432
  bf16* pb = (bf16*)(ws + 100663296);         //   4,194,304  (pbT [nh][n][g])
  bf16* ab = (bf16*)(ws + 104857600);         //   4,194,304
  bf16* aT = (bf16*)(ws + 109051904);         //     524,288
  bf16* attnT = (bf16*)(ws + 109576192);      //     524,288
  bf16* outa = (bf16*)(ws + 110100480);       //  33,554,432 (earlier xT + part)
  bf16* wqb = (bf16*)(ws + 143654912);        //     393,216
  bf16* wpb = (bf16*)(ws + 144048128);        //     131,072
  float* shq = (float*)(ws + 144179200);      //       4,096
  float* shp = (float*)(ws + 144183296);      //       4,096 -> 144,187,392
  bf16* xT = outa;                             // alias: dead before attn1
  bf16* houT = kT;                             // alias: kT dead after attn1
  float* part = (float*)outa;                  // partials, dead before attn2

  prep_w_kernel<<<1024, 256, 0, stream>>>(qkv_w, qkv_bn, proj_w, proj_bn,
                                          wqb, shq, wpb, shp);
  bias_pb_kernel<<<dim3(8, 64), 256, 0, stream>>>(an_bias, ah_bias, aw_bias, pb);
  bias_ab_kernel<<<8192, 256, 0, stream>>>(na_bias, ha_bias, wa_bias, ab);
  transpose_x_kernel<<<dim3(16, 64, 4), 256, 0, stream>>>(x, xT);
  qkv_gemm_kernel<<<dim3(32, 6, 16), 256, 0, stream>>>(xT, wqb, shq, qT, kT, vv);
  pool_kernel<<<1024, 256, 0, stream>>>(qT, aT);
  attn1_kernel<<<dim3(TILES1_, 128), 256, 0, stream>>>(kT, vv, aT, pb, part);
  attn1_combine_kernel<<<128, 256, 0, stream>>>(part, attnT);
  attn2_kernel<<<dim3(16, 128), 256, 0, stream>>>(qT, aT, attnT, ab, outa);
  pe_tr_kernel<<<dim3(16, 64, 4), 256, 0, stream>>>(vv, outa, pe_w, pe_bn, houT);
  proj_gemm_kernel<<<dim3(32, 2, 16), 256, 0, stream>>>(houT, wpb, shp,
                                                        (float*)d_out);
}

// Round 11
// 347.114 us; speedup vs baseline: 1.0182x; 1.0182x over previous
//
#include <hip/hip_runtime.h>
#include <cmath>

// ---------------------------------------------------------------------------
// Agent-attention block, MI355X gfx950.  Round 15: attn1 swapped QK^T
// (MFMA(K,A) -> n on quad*4+r, g on l16): n-reduction becomes in-reg + 2-shfl
// quad tree (was 4x 4-shfl trees per mi).  T12's "reduction-axis lane-local".
// GEMMs: BK=64 single-buffer 2-barrier discipline + G4 swizzle (round 11).
// qkv channel layout: per head nh, q = nh*96+[0,32), k = +[32,64), v = +[64,96).
// ---------------------------------------------------------------------------

typedef __bf16 bf16;
typedef bf16 bf16x8 __attribute__((ext_vector_type(8)));
typedef float f32x4 __attribute__((ext_vector_type(4)));

__device__ __forceinline__ f32x4 MFMA16(bf16x8 a, bf16x8 b, f32x4 c) {
  return __builtin_amdgcn_mfma_f32_16x16x32_bf16(a, b, c, 0, 0, 0);
}

// async global->LDS, 16B per lane; LDS dst = base + lane*16 (wave-uniform base)
__device__ __forceinline__ void gll16(const bf16* g, bf16* l) {
  __builtin_amdgcn_global_load_lds(
      (const __attribute__((address_space(1))) void*)g,
      (__attribute__((address_space(3))) void*)l, 16, 0, 0);
}

constexpr int B_ = 16, C_ = 256, N_ = 4096;
constexpr int NH_ = 8, KD_ = 32, AG_ = 64, O3_ = 768;
constexpr int TILES1_ = 4;                   // attn1 split-N tiles (measured best)
constexpr int PSTRIDE_ = 64 + 64 + 64 * 32;  // 2176 floats per (bh,tile) partial
constexpr float SCALE_ = 0.17677669529663687f;  // 32^-0.5

// ------------------------- prep_w: BN-fold + bf16 --------------------------
__global__ __launch_bounds__(256) void prep_w_kernel(
    const float* __restrict__ qkv_w, const float* __restrict__ qkv_bn,
    const float* __restrict__ proj_w, const float* __restrict__ proj_bn,
    bf16* __restrict__ wqb, float* __restrict__ shq,
    bf16* __restrict__ wpb, float* __restrict__ shp) {
  int o = blockIdx.x, t = threadIdx.x;
  if (o < O3_) {
    float g = qkv_bn[o], bb = qkv_bn[O3_ + o], m = qkv_bn[2 * O3_ + o],
          v = qkv_bn[3 * O3_ + o];
    float s = g * rsqrtf(v + 1e-5f);
    wqb[(size_t)o * C_ + t] = (bf16)(qkv_w[(size_t)o * C_ + t] * s);
    if (t == 0) shq[o] = bb - m * s;
  } else {
    int p = o - O3_;
    float g = proj_bn[p], bb = proj_bn[C_ + p], m = proj_bn[2 * C_ + p],
          v = proj_bn[3 * C_ + p];
    float s = g * rsqrtf(v + 1e-5f);
    wpb[(size_t)p * C_ + t] = (bf16)(proj_w[(size_t)p * C_ + t] * s);
    if (t == 0) shp[p] = bb - m * s;
  }
}

// ------------------------------ bias kernels -------------------------------
// pbT layout [nh][n][g].  Block = (nh, 64-n tile); lane = n_local so
// ah is broadcast, aw coalesced, an bilerp corners broadcast (g uniform per
// iteration).  LDS [64][72] (144B stride: 16B-aligned rows), coalesced
// 2x4KB write-out.
__global__ __launch_bounds__(256) void bias_pb_kernel(
    const float* __restrict__ an, const float* __restrict__ ah,
    const float* __restrict__ aw, bf16* __restrict__ pbT) {
  __shared__ __align__(16) bf16 T[64][72];
  int nh = blockIdx.x, n0 = blockIdx.y * 64;
  int t = threadIdx.x, lane = t & 63, wave = t >> 6;
  int h = n0 >> 6;  // uniform (n0 is 64-aligned)
  int w = lane;
  float fy = (h + 0.5f) * (7.0f / 64.0f) - 0.5f;
  float fx = (w + 0.5f) * (7.0f / 64.0f) - 0.5f;
  float fy0 = floorf(fy), fx0 = floorf(fx);
  float wy = fy - fy0, wx = fx - fx0;
  int y0 = (int)fy0, x0 = (int)fx0;
  int y0c = min(max(y0, 0), 6), y1c = min(max(y0 + 1, 0), 6);
  int x0c = min(max(x0, 0), 6), x1c = min(max(x0 + 1, 0), 6);
#pragma unroll
  for (int gi = 0; gi < 16; gi++) {
    int g = wave * 16 + gi;
    const float* A = an + (nh * AG_ + g) * 49;
    float a00 = A[y0c * 7 + x0c], a01 = A[y0c * 7 + x1c];
    float a10 = A[y1c * 7 + x0c], a11 = A[y1c * 7 + x1c];
    float v = (1.0f - wy) * ((1.0f - wx) * a00 + wx * a01) +
              wy * ((1.0f - wx) * a10 + wx * a11);
    v += ah[(nh * AG_ + g) * 64 + h] + aw[(nh * AG_ + g) * 64 + w];
    T[lane][g] = (bf16)v;
  }
  __syncthreads();
  bf16* dst = pbT + ((size_t)nh * N_ + n0) * AG_;
#pragma unroll
  for (int p = 0; p < 2; p++) {
    int u = p * 256 + t;
    int row = u >> 3, seg = u & 7;
    uint4 val = *(const uint4*)&T[row][seg * 8];
    *(uint4*)(dst + (size_t)row * AG_ + seg * 8) = val;
  }
}

__device__ __forceinline__ float bilerp7(const float* __restrict__ A, int h, int w) {
  float fy = (h + 0.5f) * (7.0f / 64.0f) - 0.5f;
  float fx = (w + 0.5f) * (7.0f / 64.0f) - 0.5f;
  float fy0 = floorf(fy), fx0 = floorf(fx);
  float wy = fy - fy0, wx = fx - fx0;
  int y0 = (int)fy0, x0 = (int)fx0;
  int y0c = min(max(y0, 0), 6), y1c = min(max(y0 + 1, 0), 6);
  int x0c = min(max(x0, 0), 6), x1c = min(max(x0 + 1, 0), 6);
  float a00 = A[y0c * 7 + x0c], a01 = A[y0c * 7 + x1c];
  float a10 = A[y1c * 7 + x0c], a11 = A[y1c * 7 + x1c];
  return (1.0f - wy) * ((1.0f - wx) * a00 + wx * a01) +
         wy * ((1.0f - wx) * a10 + wx * a11);
}

__global__ __launch_bounds__(256) void bias_ab_kernel(
    const float* __restrict__ na, const float* __restrict__ ha,
    const float* __restrict__ wa, bf16* __restrict__ ab) {
  int tid = blockIdx.x * 256 + threadIdx.x;  // nh,n,g  (g fastest)
  int g = tid & 63;
  int n = (tid >> 6) & (N_ - 1);
  int nh = tid >> 18;
  int h = n >> 6, w = n & 63;
  float v = bilerp7(na + (nh * AG_ + g) * 49, h, w);
  ab[tid] = (bf16)(v + ha[(nh * 64 + h) * AG_ + g] + wa[(nh * 64 + w) * AG_ + g]);
}

// --------------------- transpose_x: [c][n] f32 -> [n][c] bf16 --------------
__global__ __launch_bounds__(256) void transpose_x_kernel(
    const float* __restrict__ x, bf16* __restrict__ xT) {
  __shared__ __align__(16) unsigned LDSd[64 * 36];
  int b = blockIdx.x, n0 = blockIdx.y * 64, c0 = blockIdx.z * 64;
  int t = threadIdx.x, n = t & 63, cp = t >> 6;
  const float* xb = x + ((size_t)b * C_ + c0) * N_ + n0;
#pragma unroll
  for (int j = 0; j < 8; j++) {
    int cpr = cp * 8 + j;  // c-pair index 0..31
    int c = cpr * 2;
    float f0 = xb[(size_t)c * N_ + n];
    float f1 = xb[(size_t)(c + 1) * N_ + n];
    union { bf16 h[2]; unsigned u; } pk;
    pk.h[0] = (bf16)f0; pk.h[1] = (bf16)f1;
    LDSd[n * 36 + cpr] = pk.u;
  }
  __syncthreads();
  int n2 = t >> 2, seg = t & 3;
  const unsigned* row = &LDSd[n2 * 36 + seg * 8];
  uint4 d0 = *(const uint4*)row;
  uint4 d1 = *(const uint4*)(row + 4);
  bf16* dst = xT + ((size_t)b * N_ + n0 + n2) * C_ + c0 + seg * 16;
  *(uint4*)dst = d0;
  *(uint4*)(dst + 8) = d1;
}

// ------------------------------ K1: qkv GEMM -------------------------------
// BK=64, single-buffer, 2 barriers/K-step, G4 swizzle (verified round 11).
__global__ __launch_bounds__(256) void qkv_gemm_kernel(
    const bf16* __restrict__ xT, const bf16* __restrict__ wqb,
    const float* __restrict__ shq, bf16* __restrict__ qT,
    bf16* __restrict__ kT, bf16* __restrict__ vv) {
  int nt = blockIdx.x * 128, ot = blockIdx.y * 128, b = blockIdx.z;
  __shared__ __align__(16) bf16 As[128][64];
  __shared__ __align__(16) bf16 Bs[128][64];
  int t = threadIdx.x, wave = t >> 6, lane = t & 63, quad = lane >> 4, l16 = lane & 15;
  int wm = (wave >> 1) * 64, wn = (wave & 1) * 64;
  int lr = lane >> 3;                                // row within 8-row gll group
  int lsw = ((lane & 7) ^ (lr & 7)) * 8;             // swizzled global elem col
  f32x4 acc[4][4];
#pragma unroll
  for (int mi = 0; mi < 4; mi++)
#pragma unroll
    for (int ni = 0; ni < 4; ni++) acc[mi][ni] = (f32x4){0.f, 0.f, 0.f, 0.f};
  const bf16* xTb = xT + (size_t)b * N_ * C_;
  for (int k0 = 0; k0 < 256; k0 += 64) {
    __syncthreads();
#pragma unroll
    for (int i = 0; i < 4; i++) {
      int r0 = wave * 32 + i * 8;  // 8-aligned
      gll16(wqb + (size_t)(ot + r0 + lr) * C_ + k0 + lsw, &As[r0][0]);
      gll16(xTb + (size_t)(nt + r0 + lr) * C_ + k0 + lsw, &Bs[r0][0]);
    }
    __syncthreads();
#pragma unroll
    for (int ks2 = 0; ks2 < 2; ks2++) {
      bf16x8 af[4], bfv[4];
#pragma unroll
      for (int mi = 0; mi < 4; mi++)
        af[mi] = *(const bf16x8*)&As[wm + mi * 16 + l16]
                                   [((ks2 * 4 + quad) ^ (l16 & 7)) * 8];
#pragma unroll
      for (int ni = 0; ni < 4; ni++)
        bfv[ni] = *(const bf16x8*)&Bs[wn + ni * 16 + l16]
                                    [((ks2 * 4 + quad) ^ (l16 & 7)) * 8];
#pragma unroll
      for (int mi = 0; mi < 4; mi++)
#pragma unroll
        for (int ni = 0; ni < 4; ni++)
          acc[mi][ni] = MFMA16(af[mi], bfv[ni], acc[mi][ni]);
    }
  }
#pragma unroll
  for (int mi = 0; mi < 4; mi++) {
    int o0 = ot + wm + mi * 16 + quad * 4;
    float4 s4 = *(const float4*)(shq + o0);
    float sh[4] = {s4.x, s4.y, s4.z, s4.w};
    int base16 = ot + wm + mi * 16;  // wave-uniform, 16-aligned
    int nh = base16 / 96;
    int rem = base16 % 96;
    int type = rem >> 5;             // 0=q, 1=k, 2=v
    int kdb = (rem & 31) + quad * 4; // kd of r=0
    if (type < 2) {
      bf16* dst = (type == 0 ? qT : kT) + ((size_t)(b * NH_ + nh) * N_) * KD_;
#pragma unroll
      for (int ni = 0; ni < 4; ni++) {
        int n = nt + wn + ni * 16 + l16;
        union { ushort4 u; bf16 e[4]; } pk;
#pragma unroll
        for (int r = 0; r < 4; r++) pk.e[r] = (bf16)(acc[mi][ni][r] + sh[r]);
        *(ushort4*)(dst + (size_t)n * KD_ + kdb) = pk.u;
      }
    } else {
      bf16* dst = vv + ((size_t)(b * NH_ + nh) * KD_) * N_;
#pragma unroll
      for (int ni = 0; ni < 4; ni++) {
        int n = nt + wn + ni * 16 + l16;
#pragma unroll
        for (int r = 0; r < 4; r++)
          dst[(size_t)(kdb + r) * N_ + n] = (bf16)(acc[mi][ni][r] + sh[r]);
      }
    }
  }
}

// ------------------------------ K2: agent pooling --------------------------
__global__ __launch_bounds__(256) void pool_kernel(
    const bf16* __restrict__ qT, bf16* __restrict__ aT) {
  int tid = blockIdx.x * 256 + threadIdx.x;  // (((b*8+nh2)*64+g)*32+kd2)
  int kd2 = tid & 31;
  int g = (tid >> 5) & 63;
  int nh2 = (tid >> 11) & 7;
  int b = tid >> 14;
  int c = nh2 * KD_ + kd2;
  int ho = g >> 3, wo = g & 7;
  int ww = c & 63, ch = c >> 6;
  const bf16* qb = qT + ((size_t)(b * NH_ + ho) * N_) * KD_;
  float s = 0.f;
#pragma unroll
  for (int wi = 0; wi < 8; wi++) {
    int w_ = wo * 8 + wi;
    int n1 = ((w_ & 15) * 4 + ch) * 64 + ww;
    int kdlo = w_ >> 4;
#pragma unroll
    for (int hi = 0; hi < 8; hi++)
      s += (float)qb[(size_t)n1 * KD_ + kdlo + hi * 4];
  }
  aT[tid] = (bf16)(s * (1.0f / 64.0f));
}

// ------------------------------ K3: attn1 flash-style, swapped QK^T --------
// Grid (TILES1_=4, 128).  Per block: 1024 n; per wave: 4 online iterations.
// Swapped MFMA(K,A): s value (ni,r) at lane (quad,l16) = P[n][g] with
//   n = ng + ni*16 + quad*4 + r,  g = mi*16 + l16.
// n-reduction = 16 in-reg + 2-shfl quad tree (was 4x 4-shfl l16 trees).
// m/l are one scalar per mi (per-lane g).  Rescale factor redistributed to
// oacc's g=quad*4+r holders via 4 __shfl (bpermute).  Ps written in the same
// logical [g-row][n-col] layout the PV read consumes (unchanged PV/epilogue).
struct SM3comb { float m[4][64]; float l[4][64]; float o[4][64][33]; };
union SM3u { bf16 Ps[4][64][72]; SM3comb c; };

__global__ __launch_bounds__(256) void attn1_kernel(
    const bf16* __restrict__ kT, const bf16* __restrict__ vv,
    const bf16* __restrict__ aT, const bf16* __restrict__ pbT,
    float* __restrict__ part) {
  __shared__ __align__(16) SM3u sm;
  int tile = blockIdx.x, bh = blockIdx.y, nh = bh & 7;
  int t = threadIdx.x, wave = t >> 6, lane = t & 63, quad = lane >> 4, l16 = lane & 15;
  const bf16* aTb = aT + (size_t)bh * (AG_ * KD_);
  const bf16* kb = kT + (size_t)bh * N_ * KD_;
  const bf16* vb = vv + (size_t)bh * KD_ * N_;
  const bf16* pbh = pbT + (size_t)nh * N_ * AG_;  // [n][g]
  bf16x8 af[4];
#pragma unroll
  for (int mi = 0; mi < 4; mi++)
    af[mi] = *(const bf16x8*)(aTb + (mi * 16 + l16) * KD_ + quad * 8);
  float mrow[4], lrow[4];
  f32x4 zero4 = (f32x4){0.f, 0.f, 0.f, 0.f};
  f32x4 oacc[4][2];
#pragma unroll
  for (int mi = 0; mi < 4; mi++) {
    oacc[mi][0] = zero4; oacc[mi][1] = zero4;
    mrow[mi] = -1e30f; lrow[mi] = 0.f;
  }
  for (int it = 0; it < 4; it++) {
    int ng = tile * 1024 + wave * 256 + it * 64;
    bf16x8 kf[4];
#pragma unroll
    for (int ni = 0; ni < 4; ni++)
      kf[ni] = *(const bf16x8*)(kb + (size_t)(ng + ni * 16 + l16) * KD_ + quad * 8);
#pragma unroll
    for (int mi = 0; mi < 4; mi++) {
      int g = mi * 16 + l16;
      f32x4 s[4];
#pragma unroll
      for (int ni = 0; ni < 4; ni++) s[ni] = MFMA16(kf[ni], af[mi], zero4);
#pragma unroll
      for (int ni = 0; ni < 4; ni++)
#pragma unroll
        for (int r = 0; r < 4; r++)
          s[ni][r] = s[ni][r] * SCALE_ +
                     (float)pbh[(size_t)(ng + ni * 16 + quad * 4 + r) * AG_ + g];
      // online softmax over n: 16 in-reg + quad tree (xor 16, 32)
      float mx = s[0][0];
#pragma unroll
      for (int ni = 0; ni < 4; ni++)
#pragma unroll
        for (int r = 0; r < 4; r++) mx = fmaxf(mx, s[ni][r]);
      mx = fmaxf(mx, __shfl_xor(mx, 16));
      mx = fmaxf(mx, __shfl_xor(mx, 32));
      float newm = fmaxf(mrow[mi], mx);
      float rs = 0.f;
#pragma unroll
      for (int ni = 0; ni < 4; ni++)
#pragma unroll
        for (int r = 0; r < 4; r++) {
          float pv = __expf(s[ni][r] - newm);
          s[ni][r] = pv; rs += pv;
        }
      rs += __shfl_xor(rs, 16);
      rs += __shfl_xor(rs, 32);
      float f = __expf(mrow[mi] - newm);
      lrow[mi] = lrow[mi] * f + rs;
      mrow[mi] = newm;
      // redistribute f (per l16=g) to oacc's g = quad*4+r holders
      float fr[4];
#pragma unroll
      for (int r = 0; r < 4; r++) fr[r] = __shfl(f, quad * 4 + r);
#pragma unroll
      for (int ci = 0; ci < 2; ci++)
#pragma unroll
        for (int r = 0; r < 4; r++) oacc[mi][ci][r] *= fr[r];
      // Ps in [g-row][n-col] layout (same logical content as before)
#pragma unroll
      for (int ni = 0; ni < 4; ni++)
#pragma unroll
        for (int r = 0; r < 4; r++)
          sm.Ps[wave][mi * 16 + l16][ni * 16 + quad * 4 + r] = (bf16)s[ni][r];
    }
#pragma unroll
    for (int ks = 0; ks < 2; ks++) {
      bf16x8 vf[2], pf[4];
#pragma unroll
      for (int ci = 0; ci < 2; ci++)
        vf[ci] = *(const bf16x8*)(vb + (size_t)(ci * 16 + l16) * N_ + ng + ks * 32 + quad * 8);
#pragma unroll
      for (int mi = 0; mi < 4; mi++)
        pf[mi] = *(const bf16x8*)&sm.Ps[wave][mi * 16 + l16][ks * 32 + quad * 8];
#pragma unroll
      for (int mi = 0; mi < 4; mi++)
#pragma unroll
        for (int ci = 0; ci < 2; ci++)
          oacc[mi][ci] = MFMA16(pf[mi], vf[ci], oacc[mi][ci]);
    }
  }
  __syncthreads();  // all waves done with Ps; union switches to comb
#pragma unroll
  for (int mi = 0; mi < 4; mi++) {
    if (quad == 0) {
      sm.c.m[wave][mi * 16 + l16] = mrow[mi];
      sm.c.l[wave][mi * 16 + l16] = lrow[mi];
    }
#pragma unroll
    for (int r = 0; r < 4; r++) {
      int g = mi * 16 + quad * 4 + r;
      sm.c.o[wave][g][l16] = oacc[mi][0][r];
      sm.c.o[wave][g][16 + l16] = oacc[mi][1][r];
    }
  }
  __syncthreads();
  {
    int g = t >> 2, kd0 = (t & 3) * 8;
    float M = fmaxf(fmaxf(sm.c.m[0][g], sm.c.m[1][g]), fmaxf(sm.c.m[2][g], sm.c.m[3][g]));
    float ew[4], L = 0.f;
#pragma unroll
    for (int w2 = 0; w2 < 4; w2++) {
      ew[w2] = __expf(sm.c.m[w2][g] - M);
      L += sm.c.l[w2][g] * ew[w2];
    }
    float* pt = part + (size_t)(bh * TILES1_ + tile) * PSTRIDE_;
    if ((t & 3) == 0) { pt[g] = M; pt[64 + g] = L; }
    float4 o0, o1;
    o0.x = o0.y = o0.z = o0.w = 0.f; o1 = o0;
#pragma unroll
    for (int w2 = 0; w2 < 4; w2++) {
      float e = ew[w2];
      const float* src = &sm.c.o[w2][g][kd0];
      o0.x += src[0] * e; o0.y += src[1] * e; o0.z += src[2] * e; o0.w += src[3] * e;
      o1.x += src[4] * e; o1.y += src[5] * e; o1.z += src[6] * e; o1.w += src[7] * e;
    }
    *(float4*)(pt + 128 + g * 32 + kd0) = o0;
    *(float4*)(pt + 128 + g * 32 + kd0 + 4) = o1;
  }
}

// ------------------------------ K3b: combine partials ----------------------
__global__ __launch_bounds__(256) void attn1_combine_kernel(
    const float* __restrict__ part, bf16* __restrict__ attnT) {
  int bh = blockIdx.x, t = threadIdx.x;
  int g = t >> 2, kd0 = (t & 3) * 8;
  const float* base = part + (size_t)bh * TILES1_ * PSTRIDE_;
  float gm = -1e30f, L = 0.f;
  float o[8];
#pragma unroll
  for (int j = 0; j < 8; j++) o[j] = 0.f;
  for (int tl = 0; tl < TILES1_; tl++) {
    const float* pt = base + tl * PSTRIDE_;
    float m = pt[g], l = pt[64 + g];
    float nm = fmaxf(gm, m);
    float a0 = __expf(gm - nm), a1 = __expf(m - nm);
    L = L * a0 + l * a1;
    float4 x0 = *(const float4*)(pt + 128 + g * 32 + kd0);
    float4 x1 = *(const float4*)(pt + 128 + g * 32 + kd0 + 4);
    o[0] = o[0] * a0 + x0.x * a1; o[1] = o[1] * a0 + x0.y * a1;
    o[2] = o[2] * a0 + x0.z * a1; o[3] = o[3] * a0 + x0.w * a1;
    o[4] = o[4] * a0 + x1.x * a1; o[5] = o[5] * a0 + x1.y * a1;
    o[6] = o[6] * a0 + x1.z * a1; o[7] = o[7] * a0 + x1.w * a1;
    gm = nm;
  }
  float inv = 1.0f / L;
  bf16* dst = attnT + (size_t)bh * (KD_ * AG_);
#pragma unroll
  for (int j = 0; j < 8; j++)
    dst[(kd0 + j) * AG_ + g] = (bf16)(o[j] * inv);
}

// ------------------------------ K4: stage 2 --------------------------------
__global__ __launch_bounds__(256) void attn2_kernel(
    const bf16* __restrict__ qT, const bf16* __restrict__ aT,
    const bf16* __restrict__ attnT, const bf16* __restrict__ ab,
    bf16* __restrict__ outa) {
  __shared__ __align__(16) bf16 Ps[4][64][72];
  int nt = blockIdx.x * 256;
  int bh = blockIdx.y, b = bh >> 3, nh = bh & 7;
  int t = threadIdx.x, wave = t >> 6, lane = t & 63, quad = lane >> 4, l16 = lane & 15;
  const bf16* qb = qT + (size_t)bh * N_ * KD_;
  const bf16* aTb = aT + (size_t)bh * (AG_ * KD_);
  const bf16* atb = attnT + (size_t)bh * (KD_ * AG_);
  bf16x8 afr[4], tfr[2][2];
#pragma unroll
  for (int gi = 0; gi < 4; gi++)
    afr[gi] = *(const bf16x8*)(aTb + (gi * 16 + l16) * KD_ + quad * 8);
#pragma unroll
  for (int ci = 0; ci < 2; ci++)
#pragma unroll
    for (int ks = 0; ks < 2; ks++)
      tfr[ci][ks] = *(const bf16x8*)(atb + (ci * 16 + l16) * AG_ + ks * 32 + quad * 8);
  const bf16* abh = ab + (size_t)nh * N_ * AG_;
  int nloc = wave * 64;
  f32x4 zero4 = (f32x4){0.f, 0.f, 0.f, 0.f};
#pragma unroll
  for (int mi = 0; mi < 4; mi++) {
    bf16x8 qf = *(const bf16x8*)(qb + (size_t)(nt + nloc + mi * 16 + l16) * KD_ + quad * 8);
    f32x4 s[4];
#pragma unroll
    for (int gi = 0; gi < 4; gi++)
      s[gi] = MFMA16(qf, afr[gi], zero4);
    int n0 = nt + nloc + mi * 16 + quad * 4;
#pragma unroll
    for (int gi = 0; gi < 4; gi++) {
      int g = gi * 16 + l16;
#pragma unroll
      for (int r = 0; r < 4; r++)
        s[gi][r] = s[gi][r] * SCALE_ + (float)abh[(size_t)(n0 + r) * AG_ + g];
    }
#pragma unroll
    for (int r = 0; r < 4; r++) {
      float mx = fmaxf(fmaxf(s[0][r], s[1][r]), fmaxf(s[2][r], s[3][r]));
#pragma unroll
      for (int off = 1; off < 16; off <<= 1) mx = fmaxf(mx, __shfl_xor(mx, off));
      float rs = 0.f;
#pragma unroll
      for (int gi = 0; gi < 4; gi++) {
        float p = __expf(s[gi][r] - mx);
        s[gi][r] = p; rs += p;
      }
#pragma unroll
      for (int off = 1; off < 16; off <<= 1) rs += __shfl_xor(rs, off);
      float inv = 1.0f / rs;
#pragma unroll
      for (int gi = 0; gi < 4; gi++) s[gi][r] *= inv;
    }
#pragma unroll
    for (int gi = 0; gi < 4; gi++)
#pragma unroll
      for (int r = 0; r < 4; r++)
        Ps[wave][mi * 16 + quad * 4 + r][gi * 16 + l16] = (bf16)s[gi][r];
  }
  __syncthreads();
  f32x4 O[4][2];
#pragma unroll
  for (int mi = 0; mi < 4; mi++) { O[mi][0] = zero4; O[mi][1] = zero4; }
#pragma unroll
  for (int ks = 0; ks < 2; ks++) {
    bf16x8 pf[4];
#pragma unroll
    for (int mi = 0; mi < 4; mi++)
      pf[mi] = *(const bf16x8*)&Ps[wave][mi * 16 + l16][ks * 32 + quad * 8];
#pragma unroll
    for (int mi = 0; mi < 4; mi++)
#pragma unroll
      for (int ci = 0; ci < 2; ci++)
        O[mi][ci] = MFMA16(pf[mi], tfr[ci][ks], O[mi][ci]);
  }
  bf16* ob = outa + (size_t)b * C_ * N_;
#pragma unroll
  for (int mi = 0; mi < 4; mi++) {
    int n0 = nt + nloc + mi * 16 + quad * 4;
#pragma unroll
    for (int ci = 0; ci < 2; ci++) {
      int c = nh * KD_ + ci * 16 + l16;
      union { ushort4 u; bf16 e[4]; } pk;
#pragma unroll
      for (int r = 0; r < 4; r++) pk.e[r] = (bf16)O[mi][ci][r];
      *(ushort4*)(ob + (size_t)c * N_ + n0) = pk.u;
    }
  }
}

// -------------- K5: fused pe dwconv + add + transpose (LDS-staged) ---------
__global__ __launch_bounds__(256) void pe_tr_kernel(
    const bf16* __restrict__ vv, const bf16* __restrict__ outa,
    const float* __restrict__ pw, const float* __restrict__ bn,
    bf16* __restrict__ hT) {
  __shared__ __align__(16) bf16 Vs[3][64][68];
  __shared__ __align__(16) bf16 Os[64][68];
  int b = blockIdx.x, n0 = blockIdx.y * 64, c0 = blockIdx.z * 64;
  int h = n0 >> 6;
  int t = threadIdx.x;
#pragma unroll
  for (int dy = 0; dy < 3; dy++) {
    int hh = h + dy - 1;
    bool ok = (unsigned)hh < 64u;
#pragma unroll
    for (int it = 0; it < 2; it++) {
      int u = it * 256 + t;
      int c = u >> 3, seg = u & 7;  // 64 c x 8 segs of 16B
      union { uint4 q; uint2 d[2]; } val;
      val.q = make_uint4(0u, 0u, 0u, 0u);
      if (ok)
        val.q = *(const uint4*)(vv + ((size_t)b * C_ + c0 + c) * N_ + hh * 64 + seg * 8);
      *(uint2*)&Vs[dy][c][seg * 8] = val.d[0];
      *(uint2*)&Vs[dy][c][seg * 8 + 4] = val.d[1];
    }
  }
#pragma unroll
  for (int it = 0; it < 2; it++) {
    int u = it * 256 + t;
    int c = u >> 3, seg = u & 7;
    union { uint4 q; uint2 d[2]; } val;
    val.q = *(const uint4*)(outa + ((size_t)b * C_ + c0 + c) * N_ + n0 + seg * 8);
    *(uint2*)&Os[c][seg * 8] = val.d[0];
    *(uint2*)&Os[c][seg * 8 + 4] = val.d[1];
  }
  __syncthreads();
  int cl = t & 63, wv = t >> 6;
  int c = c0 + cl;
  const float* wc = pw + c * 9;
  float w00 = wc[0], w01 = wc[1], w02 = wc[2];
  float w10 = wc[3], w11 = wc[4], w12 = wc[5];
  float w20 = wc[6], w21 = wc[7], w22 = wc[8];
  float sc = bn[c] * rsqrtf(bn[3 * C_ + c] + 1e-5f);
  float sh = bn[C_ + c] - bn[2 * C_ + c] * sc;
#pragma unroll
  for (int half = 0; half < 2; half++) {
    int oct = half * 4 + wv;   // 0..7, wave-uniform
    int w0 = oct * 8;
    float r[3][10];
#pragma unroll
    for (int dy = 0; dy < 3; dy++) {
      union { uint2 q; bf16 e[4]; } lo, hi;
      lo.q = *(const uint2*)&Vs[dy][cl][w0];
      hi.q = *(const uint2*)&Vs[dy][cl][w0 + 4];
#pragma unroll
      for (int j = 0; j < 4; j++) {
        r[dy][j + 1] = (float)lo.e[j];
        r[dy][j + 5] = (float)hi.e[j];
      }
      r[dy][0] = (w0 > 0) ? (float)Vs[dy][cl][w0 - 1] : 0.f;
      r[dy][9] = (w0 < 56) ? (float)Vs[dy][cl][w0 + 8] : 0.f;
    }
    union { uint2 q; bf16 e[4]; } plo, phi;
    plo.q = *(const uint2*)&Os[cl][w0];
    phi.q = *(const uint2*)&Os[cl][w0 + 4];
    bf16* dst = hT + ((size_t)b * N_ + n0 + w0) * C_ + c;
#pragma unroll
    for (int j = 0; j < 8; j++) {
      float a = r[0][j] * w00 + r[0][j + 1] * w01 + r[0][j + 2] * w02 +
                r[1][j] * w10 + r[1][j + 1] * w11 + r[1][j + 2] * w12 +
                r[2][j] * w20 + r[2][j + 1] * w21 + r[2][j + 2] * w22;
      float po = (j < 4) ? (float)plo.e[j] : (float)phi.e[j - 4];
      dst[(size_t)j * C_] = (bf16)(po + a * sc + sh);
    }
  }
}

// ------------------------------ K6: proj GEMM -------------------------------
__global__ __launch_bounds__(256) void proj_gemm_kernel(
    const bf16* __restrict__ hT, const bf16* __restrict__ wpb,
    const float* __restrict__ shp, float* __restrict__ out) {
  int nt = blockIdx.x * 128, ot = blockIdx.y * 128, b = blockIdx.z;
  __shared__ __align__(16) bf16 As[128][64];
  __shared__ __align__(16) bf16 Bs[128][64];
  int t = threadIdx.x, wave = t >> 6, lane = t & 63, quad = lane >> 4, l16 = lane & 15;
  int wm = (wave >> 1) * 64, wn = (wave & 1) * 64;
  int lr = lane >> 3;
  int lsw = ((lane & 7) ^ (lr & 7)) * 8;
  f32x4 acc[4][4];
#pragma unroll
  for (int mi = 0; mi < 4; mi++)
#pragma unroll
    for (int ni = 0; ni < 4; ni++) acc[mi][ni] = (f32x4){0.f, 0.f, 0.f, 0.f};
  const bf16* hTb = hT + (size_t)b * N_ * C_;
  for (int k0 = 0; k0 < 256; k0 += 64) {
    __syncthreads();
#pragma unroll
    for (int i = 0; i < 4; i++) {
      int r0 = wave * 32 + i * 8;
      gll16(wpb + (size_t)(ot + r0 + lr) * C_ + k0 + lsw, &As[r0][0]);
      gll16(hTb + (size_t)(nt + r0 + lr) * C_ + k0 + lsw, &Bs[r0][0]);
    }
    __syncthreads();
#pragma unroll
    for (int ks2 = 0; ks2 < 2; ks2++) {
      bf16x8 af[4], bfv[4];
#pragma unroll
      for (int mi = 0; mi < 4; mi++)
        af[mi] = *(const bf16x8*)&As[wm + mi * 16 + l16]
                                   [((ks2 * 4 + quad) ^ (l16 & 7)) * 8];
#pragma unroll
      for (int ni = 0; ni < 4; ni++)
        bfv[ni] = *(const bf16x8*)&Bs[wn + ni * 16 + l16]
                                    [((ks2 * 4 + quad) ^ (l16 & 7)) * 8];
#pragma unroll
      for (int mi = 0; mi < 4; mi++)
#pragma unroll
        for (int ni = 0; ni < 4; ni++)
          acc[mi][ni] = MFMA16(af[mi], bfv[ni], acc[mi][ni]);
    }
  }
  float* ob = out + (size_t)b * C_ * N_;
#pragma unroll
  for (int mi = 0; mi < 4; mi++) {
    int o0 = ot + wm + mi * 16 + quad * 4;
    float4 s4 = *(const float4*)(shp + o0);
    float sh[4] = {s4.x, s4.y, s4.z, s4.w};
#pragma unroll
    for (int ni = 0; ni < 4; ni++) {
      int n = nt + wn + ni * 16 + l16;
#pragma unroll
      for (int r = 0; r < 4; r++)
        ob[(size_t)(o0 + r) * N_ + n] = acc[mi][ni][r] + sh[r];
    }
  }
}

// ------------------------------ launcher -----------------------------------
extern "C" void kernel_launch(void* const* d_in, const int* in_sizes, int n_in,
                              void* d_out, int out_size, void* d_ws, size_t ws_size,
                              hipStream_t stream) {
  const float* x = (const float*)d_in[0];
  const float* qkv_w = (const float*)d_in[1];
  const float* qkv_bn = (const float*)d_in[2];
  const float* pe_w = (const float*)d_in[3];
  const float* pe_bn = (const float*)d_in[4];
  const float* proj_w = (const float*)d_in[5];
  const float* proj_bn = (const float*)d_in[6];
  const float* an_bias = (const float*)d_in[7];
  const float* na_bias = (const float*)d_in[8];
  const float* ah_bias = (const float*)d_in[9];
  const float* aw_bias = (const float*)d_in[10];
  const float* ha_bias = (const float*)d_in[11];
  const float* wa_bias = (const float*)d_in[12];

  char* ws = (char*)d_ws;
  bf16* qT = (bf16*)(ws + 0);                 //  33,554,432
  bf16* kT = (bf16*)(ws + 33554432);          //  33,554,432 (later houT)
  bf16* vv = (bf16*)(ws + 67108864);          //  33,554,432
  bf16* pb = (bf16*)(ws + 100663296);         //   4,194,304  (pbT [nh][n][g])
  bf16* ab = (bf16*)(ws + 104857600);         //   4,194,304
  bf16* aT = (bf16*)(ws + 109051904);         //     524,288
  bf16* attnT = (bf16*)(ws + 109576192);      //     524,288
  bf16* outa = (bf16*)(ws + 110100480);       //  33,554,432 (earlier xT + part)
  bf16* wqb = (bf16*)(ws + 143654912);        //     393,216
  bf16* wpb = (bf16*)(ws + 144048128);        //     131,072
  float* shq = (float*)(ws + 144179200);      //       4,096
  float* shp = (float*)(ws + 144183296);      //       4,096 -> 144,187,392
  bf16* xT = outa;                             // alias: dead before attn1
  bf16* houT = kT;                             // alias: kT dead after attn1
  float* part = (float*)outa;                  // partials, dead before attn2

  prep_w_kernel<<<1024, 256, 0, stream>>>(qkv_w, qkv_bn, proj_w, proj_bn,
                                          wqb, shq, wpb, shp);
  bias_pb_kernel<<<dim3(8, 64), 256, 0, stream>>>(an_bias, ah_bias, aw_bias, pb);
  bias_ab_kernel<<<8192, 256, 0, stream>>>(na_bias, ha_bias, wa_bias, ab);
  transpose_x_kernel<<<dim3(16, 64, 4), 256, 0, stream>>>(x, xT);
  qkv_gemm_kernel<<<dim3(32, 6, 16), 256, 0, stream>>>(xT, wqb, shq, qT, kT, vv);
  pool_kernel<<<1024, 256, 0, stream>>>(qT, aT);
  attn1_kernel<<<dim3(TILES1_, 128), 256, 0, stream>>>(kT, vv, aT, pb, part);
  attn1_combine_kernel<<<128, 256, 0, stream>>>(part, attnT);
  attn2_kernel<<<dim3(16, 128), 256, 0, stream>>>(qT, aT, attnT, ab, outa);
  pe_tr_kernel<<<dim3(16, 64, 4), 256, 0, stream>>>(vv, outa, pe_w, pe_bn, houT);
  proj_gemm_kernel<<<dim3(32, 2, 16), 256, 0, stream>>>(houT, wpb, shp,
                                                        (float*)d_out);
}